// Round 18
// baseline (113.848 us; speedup 1.0000x reference)
//
#include <hip/hip_runtime.h>
#include <hip/hip_bf16.h>

#define CC 256
#define DD 64
#define PP 18
#define ROWS 32768
#define EPSF 1e-5f

typedef __attribute__((ext_vector_type(8))) short bf16x8;
typedef __attribute__((ext_vector_type(4))) short s16x4;
typedef __attribute__((ext_vector_type(4))) float f32x4;

// ---------------------------------------------------------------------------
// Weight prep: Wq/Wk/Wv/Wo AND W1/W2 -> 16x16 MFMA fragment order (bf16):
// dst[((nt*KS + ks)*64 + l)*8 + e] = W[ks*32 + (l>>4)*8 + e][nt*16 + (l&15)]
// grid 2304: b<256 qkv+Wo; 256<=b<1280 W1 (KS=8,N=1024); else W2 (KS=32,N=256)
__global__ __launch_bounds__(256) void k_prep(
    const float* __restrict__ Wq, const float* __restrict__ Wk,
    const float* __restrict__ Wv, const float* __restrict__ Wo,
    const float* __restrict__ W1, const float* __restrict__ W2,
    __hip_bfloat16* __restrict__ WqP, __hip_bfloat16* __restrict__ WkP,
    __hip_bfloat16* __restrict__ WvP, __hip_bfloat16* __restrict__ WoP,
    __hip_bfloat16* __restrict__ W1P, __hip_bfloat16* __restrict__ W2P) {
    const int b = blockIdx.x, t = threadIdx.x;
    const float* src; __hip_bfloat16* dst; int K, N, j;
    if (b < 256) {
        int i = b * 256 + t;
        if (i < 16384)      { src = Wq; dst = WqP; K = 256; N = 64;  j = i; }
        else if (i < 32768) { src = Wk; dst = WkP; K = 256; N = 64;  j = i - 16384; }
        else if (i < 49152) { src = Wv; dst = WvP; K = 256; N = 64;  j = i - 32768; }
        else                { src = Wo; dst = WoP; K = 64;  N = 256; j = i - 49152; }
    } else if (b < 1280) {
        src = W1; dst = W1P; K = 256;  N = 1024; j = (b - 256) * 256 + t;
    } else {
        src = W2; dst = W2P; K = 1024; N = 256;  j = (b - 1280) * 256 + t;
    }
    int e = j & 7, l = (j >> 3) & 63, rest = j >> 9;
    int KS = K >> 5;
    int ks = rest % KS, nt = rest / KS;
    int row = ks * 32 + (l >> 4) * 8 + e;
    int col = nt * 16 + (l & 15);
    dst[j] = __float2bfloat16(src[(long)row * N + col]);
}

// ---------------------------------------------------------------------------
// Fused QKV. 32 rows/block, 4 waves, 16x16 MFMA, A-frags hoisted.
__global__ __launch_bounds__(256) void k_qkv(
    const float4* __restrict__ X4, const float4* __restrict__ pe4,
    const __hip_bfloat16* __restrict__ WqP, const __hip_bfloat16* __restrict__ WkP,
    const __hip_bfloat16* __restrict__ WvP,
    const float* __restrict__ bq, const float* __restrict__ bk,
    const float* __restrict__ bv,
    __hip_bfloat16* __restrict__ Xpb,
    __hip_bfloat16* __restrict__ Qb, __hip_bfloat16* __restrict__ Kb,
    __hip_bfloat16* __restrict__ Vb) {
    __shared__ short Xs[32 * 256];      // 16 KB, swizzled
    const int t = threadIdx.x, w = t >> 6, l = t & 63;
    const int l15 = l & 15, lh = l >> 4;
    const int row0 = blockIdx.x * 32;

    for (int j = t; j < 2048; j += 256) {
        int r = j >> 6, c4 = j & 63;
        long g = row0 + r;
        float4 a = X4[(g << 6) + c4];
        float4 p = pe4[(long)((g & 16383) << 6) + c4];
        union { s16x4 v; __hip_bfloat16 h[4]; } u;
        u.h[0] = __float2bfloat16(a.x + p.x);
        u.h[1] = __float2bfloat16(a.y + p.y);
        u.h[2] = __float2bfloat16(a.z + p.z);
        u.h[3] = __float2bfloat16(a.w + p.w);
        int db = (r << 9) + (c4 << 3);
        db ^= (r & 7) << 4;
        *(s16x4*)((char*)Xs + db) = u.v;
        *(s16x4*)((char*)Xpb + (g << 9) + (c4 << 3)) = u.v;
    }
    __syncthreads();

    bf16x8 af[2][8];
#pragma unroll
    for (int ri = 0; ri < 2; ++ri)
#pragma unroll
        for (int ks = 0; ks < 8; ++ks) {
            int r = ri * 16 + l15;
            int db = (r << 9) + ks * 64 + lh * 16;
            db ^= (r & 7) << 4;
            af[ri][ks] = *(const bf16x8*)((const char*)Xs + db);
        }

    f32x4 acc[3][2];
#pragma unroll
    for (int j = 0; j < 3; ++j)
#pragma unroll
        for (int ri = 0; ri < 2; ++ri) acc[j][ri] = (f32x4)(0.f);

#pragma unroll
    for (int ks = 0; ks < 8; ++ks)
#pragma unroll
        for (int j = 0; j < 3; ++j) {
            int nt = w * 3 + j;
            const __hip_bfloat16* WP = (nt < 4) ? WqP : ((nt < 8) ? WkP : WvP);
            int ntl = nt & 3;
            bf16x8 b = *(const bf16x8*)(WP + (long)(((ntl * 8 + ks) << 6) + l) * 8);
#pragma unroll
            for (int ri = 0; ri < 2; ++ri)
                acc[j][ri] = __builtin_amdgcn_mfma_f32_16x16x32_bf16(
                    af[ri][ks], b, acc[j][ri], 0, 0, 0);
        }

#pragma unroll
    for (int j = 0; j < 3; ++j) {
        int nt = w * 3 + j;
        __hip_bfloat16* OP = (nt < 4) ? Qb : ((nt < 8) ? Kb : Vb);
        const float* BP = (nt < 4) ? bq : ((nt < 8) ? bk : bv);
        int col = (nt & 3) * 16 + l15;
        float bias = BP[col];
#pragma unroll
        for (int ri = 0; ri < 2; ++ri)
#pragma unroll
            for (int rg = 0; rg < 4; ++rg) {
                long row = row0 + ri * 16 + lh * 4 + rg;
                OP[row * DD + col] = __float2bfloat16(acc[j][ri][rg] + bias);
            }
    }
}

// ---------------------------------------------------------------------------
// Gather-attention v3, wave-parallel with grouped PV. One wave per token.
__global__ __launch_bounds__(256) void k_attn(const __hip_bfloat16* __restrict__ Q,
                                              const __hip_bfloat16* __restrict__ K,
                                              const __hip_bfloat16* __restrict__ V,
                                              const int* __restrict__ sel,
                                              __hip_bfloat16* __restrict__ ctx,
                                              float* __restrict__ attn_out) {
    const int wave  = threadIdx.x >> 6;
    const int lane  = threadIdx.x & 63;
    const int token = blockIdx.x * 4 + wave;
    const int b     = token >> 14;
    const int g = lane >> 3, s = lane & 7;

    const int* selp = sel + (long)token * PP;
    int sel_l = (lane < PP) ? selp[lane] : 0;

    float qf[8];
    {
        uint4 qv = *(const uint4*)(Q + (long)token * DD + s * 8);
        qf[0] = __uint_as_float(qv.x << 16);
        qf[1] = __uint_as_float(qv.x & 0xffff0000u);
        qf[2] = __uint_as_float(qv.y << 16);
        qf[3] = __uint_as_float(qv.y & 0xffff0000u);
        qf[4] = __uint_as_float(qv.z << 16);
        qf[5] = __uint_as_float(qv.z & 0xffff0000u);
        qf[6] = __uint_as_float(qv.w << 16);
        qf[7] = __uint_as_float(qv.w & 0xffff0000u);
    }

    const __hip_bfloat16* Kbase = K + (((long)b << 14) * DD);
    float sc[3];
    int idxs[3];
#pragma unroll
    for (int i = 0; i < 3; ++i) {
        int r = i * 8 + g;
        idxs[i] = __shfl(sel_l, r);
        uint4 kv = *(const uint4*)(Kbase + (long)idxs[i] * DD + s * 8);
        float part;
        part = qf[0] * __uint_as_float(kv.x << 16);
        part = fmaf(qf[1], __uint_as_float(kv.x & 0xffff0000u), part);
        part = fmaf(qf[2], __uint_as_float(kv.y << 16), part);
        part = fmaf(qf[3], __uint_as_float(kv.y & 0xffff0000u), part);
        part = fmaf(qf[4], __uint_as_float(kv.z << 16), part);
        part = fmaf(qf[5], __uint_as_float(kv.z & 0xffff0000u), part);
        part = fmaf(qf[6], __uint_as_float(kv.w << 16), part);
        part = fmaf(qf[7], __uint_as_float(kv.w & 0xffff0000u), part);
        part += __shfl_xor(part, 1);
        part += __shfl_xor(part, 2);
        part += __shfl_xor(part, 4);
        sc[i] = (r < PP) ? part * 0.125f : -1e30f;
    }

    float m = fmaxf(fmaxf(sc[0], sc[1]), sc[2]);
    m = fmaxf(m, __shfl_xor(m, 8));
    m = fmaxf(m, __shfl_xor(m, 16));
    m = fmaxf(m, __shfl_xor(m, 32));
    const float L2E = 1.4426950408889634f;
    float e0 = exp2f((sc[0] - m) * L2E);
    float e1 = exp2f((sc[1] - m) * L2E);
    float e2 = exp2f((sc[2] - m) * L2E);
    float dsum = e0 + e1 + e2;
    dsum += __shfl_xor(dsum, 8);
    dsum += __shfl_xor(dsum, 16);
    dsum += __shfl_xor(dsum, 32);
    float inv = 1.f / dsum;

    {
        int srcl = (lane & 7) << 3;
        float b0 = __shfl(e0, srcl);
        float b1 = __shfl(e1, srcl);
        float b2 = __shfl(e2, srcl);
        if (lane < PP) {
            float ev = (lane < 8) ? b0 : ((lane < 16) ? b1 : b2);
            attn_out[(long)token * PP + lane] = ev * inv;
        }
    }

    const __hip_bfloat16* Vbase = V + (((long)b << 14) * DD);
    float ca[8];
#pragma unroll
    for (int j = 0; j < 8; ++j) ca[j] = 0.f;
    float ev3[3] = {e0, e1, e2};
#pragma unroll
    for (int i = 0; i < 3; ++i) {
        uint4 vv = *(const uint4*)(Vbase + (long)idxs[i] * DD + s * 8);
        float e = ev3[i];
        ca[0] = fmaf(e, __uint_as_float(vv.x << 16), ca[0]);
        ca[1] = fmaf(e, __uint_as_float(vv.x & 0xffff0000u), ca[1]);
        ca[2] = fmaf(e, __uint_as_float(vv.y << 16), ca[2]);
        ca[3] = fmaf(e, __uint_as_float(vv.y & 0xffff0000u), ca[3]);
        ca[4] = fmaf(e, __uint_as_float(vv.z << 16), ca[4]);
        ca[5] = fmaf(e, __uint_as_float(vv.z & 0xffff0000u), ca[5]);
        ca[6] = fmaf(e, __uint_as_float(vv.w << 16), ca[6]);
        ca[7] = fmaf(e, __uint_as_float(vv.w & 0xffff0000u), ca[7]);
    }
#pragma unroll
    for (int o = 8; o <= 32; o <<= 1)
#pragma unroll
        for (int j = 0; j < 8; ++j) ca[j] += __shfl_xor(ca[j], o);
    if (g == 0) {
        union { bf16x8 v; __hip_bfloat16 h[8]; } u;
#pragma unroll
        for (int j = 0; j < 8; ++j) u.h[j] = __float2bfloat16(ca[j] * inv);
        *(bf16x8*)(ctx + (long)token * DD + s * 8) = u.v;
    }
}

// ---------------------------------------------------------------------------
// proj + LN1: Xn = LN(Xpb + ctx@Wo + bo)*g1 + be1 -> bf16 (in-place on Xpb).
__global__ __launch_bounds__(256) void k_projln(
    const __hip_bfloat16* __restrict__ ctx, const __hip_bfloat16* __restrict__ WoP,
    const float* __restrict__ bo, const float* __restrict__ g1,
    const float* __restrict__ be1,
    const __hip_bfloat16* __restrict__ Xpb, __hip_bfloat16* __restrict__ Xnb) {
    __shared__ short Cs[32 * 64];       // 4 KB, swizzled
    __shared__ float red[2][32][2];
    __shared__ float mrs[32][2];
    const int t = threadIdx.x, w = t >> 6, l = t & 63;
    const int l15 = l & 15, lh = l >> 4;
    const int row0 = blockIdx.x * 32;

    {
        int r = t >> 3, ch = t & 7;
        int db = (r << 7) + (ch << 4);
        db ^= (r & 7) << 4;
        *(bf16x8*)((char*)Cs + db) = *(const bf16x8*)(ctx + (long)(row0 + r) * DD + ch * 8);
    }
    __syncthreads();

    const int ri = w & 1, nh = w >> 1;

    bf16x8 af[2];
#pragma unroll
    for (int ks = 0; ks < 2; ++ks) {
        int r = ri * 16 + l15;
        int db = (r << 7) + ks * 64 + lh * 16;
        db ^= (r & 7) << 4;
        af[ks] = *(const bf16x8*)((const char*)Cs + db);
    }

    f32x4 acc[8];
#pragma unroll
    for (int j = 0; j < 8; ++j) acc[j] = (f32x4)(0.f);

#pragma unroll
    for (int ks = 0; ks < 2; ++ks)
#pragma unroll
        for (int j = 0; j < 8; ++j) {
            int nt = nh * 8 + j;
            bf16x8 b = *(const bf16x8*)(WoP + (long)(((nt * 2 + ks) << 6) + l) * 8);
            acc[j] = __builtin_amdgcn_mfma_f32_16x16x32_bf16(af[ks], b, acc[j], 0, 0, 0);
        }

    float bov[8], g1v[8], be1v[8];
#pragma unroll
    for (int j = 0; j < 8; ++j) {
        int col = (nh * 8 + j) * 16 + l15;
        bov[j] = bo[col]; g1v[j] = g1[col]; be1v[j] = be1[col];
    }

    float xv[4][8];
#pragma unroll
    for (int rg = 0; rg < 4; ++rg) {
        long grow = row0 + ri * 16 + lh * 4 + rg;
        float s = 0.f, q = 0.f;
#pragma unroll
        for (int j = 0; j < 8; ++j) {
            float v = acc[j][rg] + bov[j] +
                      __bfloat162float(Xpb[grow * CC + (nh * 8 + j) * 16 + l15]);
            xv[rg][j] = v; s += v; q += v * v;
        }
#pragma unroll
        for (int o = 8; o > 0; o >>= 1) { s += __shfl_xor(s, o); q += __shfl_xor(q, o); }
        if (l15 == 0) {
            int rl = ri * 16 + lh * 4 + rg;
            red[nh][rl][0] = s; red[nh][rl][1] = q;
        }
    }
    __syncthreads();
    if (t < 32) {
        float S = red[0][t][0] + red[1][t][0];
        float Q = red[0][t][1] + red[1][t][1];
        float mu = S * (1.f / CC);
        float var = Q * (1.f / CC) - mu * mu;
        mrs[t][0] = mu; mrs[t][1] = rsqrtf(var + EPSF);
    }
    __syncthreads();
#pragma unroll
    for (int rg = 0; rg < 4; ++rg) {
        int rl = ri * 16 + lh * 4 + rg;
        long grow = row0 + rl;
        float mu = mrs[rl][0], rs = mrs[rl][1];
#pragma unroll
        for (int j = 0; j < 8; ++j)
            Xnb[grow * CC + (nh * 8 + j) * 16 + l15] =
                __float2bfloat16((xv[rg][j] - mu) * rs * g1v[j] + be1v[j]);
    }
}

// ---------------------------------------------------------------------------
// Fully fused FFN + LN2, H resident in LDS (128 KB). 64 rows/block, 512 thr,
// 8 waves, grid 512 (1 block/CU).
// Phase A (swapped operands): H^T-frags = W1frag(A) x Xfrag(B) so each lane
// holds 4 consecutive HIDDEN values -> packed b64 H-writes. No barriers.
// Phase B: out = LN(H @ W2 + b2 + Res); A from LDS, W2 frags from L2.
// No barriers inside either K-loop; one barrier between phases.
__global__ __launch_bounds__(512) void k_ffn(
    const __hip_bfloat16* __restrict__ Xn,    // [32768][256] (also residual)
    const __hip_bfloat16* __restrict__ W1P,   // frag-packed K=256 N=1024
    const float* __restrict__ b1,
    const __hip_bfloat16* __restrict__ W2P,   // frag-packed K=1024 N=256
    const float* __restrict__ b2,
    const float* __restrict__ g2, const float* __restrict__ be2,
    float* __restrict__ out) {
    __shared__ short Hs[64 * 1024];     // 128 KB; row stride 2048 B, XOR swz
    __shared__ float red[8][64][2];     // 4 KB
    __shared__ float mrs[64][2];        // 0.5 KB

    const int t = threadIdx.x, w = t >> 6, l = t & 63;
    const int l15 = l & 15, lh = l >> 4;
    const int row0 = blockIdx.x * 64;

    // ================= phase A: H = relu(X @ W1 + b1) ==================
    // wave w owns hidden cols [w*128, w*128+128). M = hidden, N = x-rows.
    {
        f32x4 hacc[8][4];
#pragma unroll
        for (int a = 0; a < 8; ++a)
#pragma unroll
            for (int f = 0; f < 4; ++f) hacc[a][f] = (f32x4)(0.f);

        const __hip_bfloat16* xb = Xn + (long)(row0 + l15) * CC + lh * 8;

#pragma unroll
        for (int ks = 0; ks < 8; ++ks) {
            bf16x8 afr[8];
#pragma unroll
            for (int a = 0; a < 8; ++a)
                afr[a] = *(const bf16x8*)(
                    W1P + (long)((((w * 8 + a) * 8 + ks) << 6) + l) * 8);
            bf16x8 xfr[4];
#pragma unroll
            for (int f = 0; f < 4; ++f)
                xfr[f] = *(const bf16x8*)(xb + f * 16 * CC + ks * 32);
#pragma unroll
            for (int a = 0; a < 8; ++a)
#pragma unroll
                for (int f = 0; f < 4; ++f)
                    hacc[a][f] = __builtin_amdgcn_mfma_f32_16x16x32_bf16(
                        afr[a], xfr[f], hacc[a][f], 0, 0, 0);
        }

        // H-write: frag (a,f): xrow = f*16+l15 (D col), hidden = w*128 +
        // a*16 + lh*4 + rg (D row). 4 consecutive hidden vals -> packed b64.
#pragma unroll
        for (int a = 0; a < 8; ++a) {
            int hid4 = w * 128 + a * 16 + lh * 4;
            float4 b1q = *(const float4*)(b1 + hid4);
#pragma unroll
            for (int f = 0; f < 4; ++f) {
                int xrow = f * 16 + l15;
                union { s16x4 v; __hip_bfloat16 h[4]; } u;
                u.h[0] = __float2bfloat16(fmaxf(hacc[a][f][0] + b1q.x, 0.f));
                u.h[1] = __float2bfloat16(fmaxf(hacc[a][f][1] + b1q.y, 0.f));
                u.h[2] = __float2bfloat16(fmaxf(hacc[a][f][2] + b1q.z, 0.f));
                u.h[3] = __float2bfloat16(fmaxf(hacc[a][f][3] + b1q.w, 0.f));
                int db = (xrow << 11) + ((hid4 * 2) ^ ((xrow & 7) << 4));
                *(s16x4*)((char*)Hs + db) = u.v;
            }
        }
    }
    __syncthreads();

    // ================= phase B: out = LN(H @ W2 + b2 + Res) =============
    // wave w owns out cols [w*32, w*32+32): j 0..1. K = 1024, BK = 64.
    f32x4 acc[4][2];
#pragma unroll
    for (int f = 0; f < 4; ++f)
#pragma unroll
        for (int j = 0; j < 2; ++j) acc[f][j] = (f32x4)(0.f);

    int offH[4][2];                      // A-frag LDS offsets per (f, kk)
#pragma unroll
    for (int f = 0; f < 4; ++f) {
        int rowA = f * 16 + l15;
        int sw = (rowA & 7) << 4;
#pragma unroll
        for (int kk = 0; kk < 2; ++kk)
            offH[f][kk] = (rowA << 11) + (((kk * 64 + lh * 16)) ^ sw);
    }

#pragma unroll 2
    for (int ks = 0; ks < 16; ++ks) {
        bf16x8 bfr[2][2];
#pragma unroll
        for (int j = 0; j < 2; ++j)
#pragma unroll
            for (int kk = 0; kk < 2; ++kk)
                bfr[j][kk] = *(const bf16x8*)(
                    W2P + (long)((((w * 2 + j) * 32 + ks * 2 + kk) << 6) + l) * 8);
        bf16x8 afr[4][2];
#pragma unroll
        for (int f = 0; f < 4; ++f)
#pragma unroll
            for (int kk = 0; kk < 2; ++kk)
                afr[f][kk] = *(const bf16x8*)((const char*)Hs + offH[f][kk] + ks * 128);
#pragma unroll
        for (int kk = 0; kk < 2; ++kk)
#pragma unroll
            for (int f = 0; f < 4; ++f)
#pragma unroll
                for (int j = 0; j < 2; ++j)
                    acc[f][j] = __builtin_amdgcn_mfma_f32_16x16x32_bf16(
                        afr[f][kk], bfr[j][kk], acc[f][j], 0, 0, 0);
    }

    // ---- epilogue: residual + LN2 ----
    float b2v[2], g2v[2], be2v[2];
#pragma unroll
    for (int j = 0; j < 2; ++j) {
        int col = w * 32 + j * 16 + l15;
        b2v[j] = b2[col]; g2v[j] = g2[col]; be2v[j] = be2[col];
    }
#pragma unroll
    for (int f = 0; f < 4; ++f)
#pragma unroll
        for (int rg = 0; rg < 4; ++rg) {
            int row = f * 16 + lh * 4 + rg;
            float s = 0.f, q = 0.f;
#pragma unroll
            for (int j = 0; j < 2; ++j) {
                long gi = (long)(row0 + row) * CC + w * 32 + j * 16 + l15;
                float v = acc[f][j][rg] + b2v[j] + __bfloat162float(Xn[gi]);
                acc[f][j][rg] = v;
                s += v; q += v * v;
            }
#pragma unroll
            for (int o = 8; o > 0; o >>= 1) {
                s += __shfl_xor(s, o); q += __shfl_xor(q, o);
            }
            if (l15 == 0) { red[w][row][0] = s; red[w][row][1] = q; }
        }
    __syncthreads();
    if (t < 64) {
        float S = 0.f, Q = 0.f;
#pragma unroll
        for (int ww = 0; ww < 8; ++ww) { S += red[ww][t][0]; Q += red[ww][t][1]; }
        float mu = S * (1.f / CC);
        float var = Q * (1.f / CC) - mu * mu;
        mrs[t][0] = mu; mrs[t][1] = rsqrtf(var + EPSF);
    }
    __syncthreads();
#pragma unroll
    for (int f = 0; f < 4; ++f)
#pragma unroll
        for (int rg = 0; rg < 4; ++rg) {
            int row = f * 16 + lh * 4 + rg;
            float mu = mrs[row][0], rs = mrs[row][1];
#pragma unroll
            for (int j = 0; j < 2; ++j) {
                long gi = (long)(row0 + row) * CC + w * 32 + j * 16 + l15;
                out[gi] = (acc[f][j][rg] - mu) * rs * g2v[j] + be2v[j];
            }
        }
}

// ---------------------------------------------------------------------------
extern "C" void kernel_launch(void* const* d_in, const int* in_sizes, int n_in,
                              void* d_out, int out_size, void* d_ws, size_t ws_size,
                              hipStream_t stream) {
    const float* X   = (const float*)d_in[0];
    const int*   sel = (const int*)d_in[1];
    const float* pe  = (const float*)d_in[3];
    const float* Wq  = (const float*)d_in[4];
    const float* bq  = (const float*)d_in[5];
    const float* Wk  = (const float*)d_in[6];
    const float* bk  = (const float*)d_in[7];
    const float* Wv  = (const float*)d_in[8];
    const float* bv  = (const float*)d_in[9];
    const float* Wo  = (const float*)d_in[10];
    const float* bo  = (const float*)d_in[11];
    const float* W1  = (const float*)d_in[12];
    const float* b1  = (const float*)d_in[13];
    const float* W2  = (const float*)d_in[14];
    const float* b2  = (const float*)d_in[15];
    const float* g1  = (const float*)d_in[16];
    const float* be1 = (const float*)d_in[17];
    const float* g2  = (const float*)d_in[18];
    const float* be2 = (const float*)d_in[19];

    float* out = (float*)d_out;
    char*  ws  = (char*)d_ws;       // ws_size ~= 256 MiB

    __hip_bfloat16* Xpb = (__hip_bfloat16*)(ws);                  // 16 MB (Xp->Xn in place)
    __hip_bfloat16* Qb  = (__hip_bfloat16*)(ws + (16 << 20));     // 4 MB
    __hip_bfloat16* Kb  = (__hip_bfloat16*)(ws + (20 << 20));     // 4 MB
    __hip_bfloat16* Vb  = (__hip_bfloat16*)(ws + (24 << 20));     // 4 MB
    __hip_bfloat16* ctxb= (__hip_bfloat16*)(ws + (28 << 20));     // 4 MB
    __hip_bfloat16* WqP = (__hip_bfloat16*)(ws + (96 << 20));     // 32 KB
    __hip_bfloat16* WkP = WqP + 16384;
    __hip_bfloat16* WvP = WkP + 16384;
    __hip_bfloat16* WoP = WvP + 16384;                            // 32 KB
    __hip_bfloat16* W1P = WoP + 16384;                            // 512 KB frag-packed
    __hip_bfloat16* W2P = W1P + 262144;                           // 512 KB frag-packed
    float* attn_out = out + (long)ROWS * CC;

    k_prep<<<2304, 256, 0, stream>>>(Wq, Wk, Wv, Wo, W1, W2,
                                     WqP, WkP, WvP, WoP, W1P, W2P);

    k_qkv<<<ROWS / 32, 256, 0, stream>>>((const float4*)X, (const float4*)pe,
                                         WqP, WkP, WvP, bq, bk, bv,
                                         Xpb, Qb, Kb, Vb);

    k_attn<<<ROWS / 4, 256, 0, stream>>>(Qb, Kb, Vb, sel, ctxb, attn_out);

    k_projln<<<ROWS / 32, 256, 0, stream>>>(ctxb, WoP, bo, g1, be1, Xpb, Xpb);

    // Fused FFN + LN2, H in LDS (no global H traffic).
    k_ffn<<<ROWS / 64, 512, 0, stream>>>(Xpb, W1P, b1, W2P, b2, g2, be2, out);
}